// Round 5
// baseline (95.236 us; speedup 1.0000x reference)
//
#include <hip/hip_runtime.h>
#include <math.h>

// ---------------------------------------------------------------------------
// FluxAnomalyPredictionTF: F=3, E=6, H=3, d=2, FF=2048, N=16, T=2046, S=W=1024
// 4 dispatches: frontend(+fcc+qkv0) -> layer0(mega) -> layer1(mega) -> final
// mega = attn(3 heads) + oproj + LN1 + FF(2048, 2-pass LDS) + LN2 + next-qkv
// ---------------------------------------------------------------------------

#define NB 16
#define TL 2046
#define SL 1024
#define ED 6

__device__ __forceinline__ float relu_(float a){ return fmaxf(a, 0.f); }
__device__ __forceinline__ float fexp2_(float x){ return __builtin_amdgcn_exp2f(x); }

#define SCQK 1.0201265650432017f  // (1/sqrt(2)) * log2(e)

// ------------------------------ frontend -----------------------------------
// grid 256 = 16 n * 16 stiles ; 192 threads = 3 waves (wave = feature f)
// Also: builds fcc; computes layer-0 qkv -> kv/qq.
__global__ __launch_bounds__(192) void frontend_kernel(
  const float* __restrict__ x, const float* __restrict__ k64,
  const float* __restrict__ b64, const float* __restrict__ k16, const float* __restrict__ b16,
  const float* __restrict__ k8,  const float* __restrict__ b8,
  const float* __restrict__ kw3, const float* __restrict__ bw3,
  const float* __restrict__ km3, const float* __restrict__ bm3,
  const float* __restrict__ kn3, const float* __restrict__ bn3,
  const float* __restrict__ fc1w, const float* __restrict__ fc1b,
  const float* __restrict__ fc2w, const float* __restrict__ fc2b,
  const float* __restrict__ f1w, const float* __restrict__ f1b,
  const float* __restrict__ f2w,
  const float* __restrict__ inw, const float* __restrict__ inb,
  float* __restrict__ fcc, float* __restrict__ seq,
  float4* __restrict__ kv4, float2* __restrict__ qq)
{
  __shared__ float xt[3][200];
  __shared__ float k64s[3*64*8];
  __shared__ float flat_s[64][44];
  __shared__ float h1_s[64][20];
  __shared__ float seq6[64][6];
  const int tid  = threadIdx.x;
  const int f    = tid >> 6;
  const int lane = tid & 63;
  const int n    = blockIdx.x >> 4;
  const int s0   = (blockIdx.x & 15) << 6;
  const int s    = s0 + lane;

  // ---- build fcc (global, for layer kernels) ----
  // fcc[l][j][16]: [0..5]=f1w row j, [6]=f1b[j], [8..13]=f2w[:,j]
  for (int i = blockIdx.x*192 + tid; i < 2*2048*16; i += 256*192){
    int l = i >> 15, r = i & 32767, j = r >> 4, c = r & 15;
    float v = 0.f;
    if (c < 6)       v = f1w[(l*2048 + j)*6 + c];
    else if (c == 6) v = f1b[l*2048 + j];
    else if (c >= 8 && c < 14) v = f2w[(l*6 + (c-8))*2048 + j];
    fcc[i] = v;
  }

  for (int i = tid; i < 600; i += 192){
    int ff = i / 200, pos = i - ff*200;
    int xp = 2*s0 - 39 + pos;
    xt[ff][pos] = (xp >= 0 && xp < TL) ? x[(n*TL + xp)*3 + ff] : 0.f;
  }
  for (int i = tid; i < 1536; i += 192){
    int ff = i >> 9, r = i & 511, t = r >> 3, k = r & 7;
    k64s[i] = k64[k*192 + ff*64 + t];
  }
  __syncthreads();

  float xr[74];
  {
    const int b = 2*lane;
    #pragma unroll
    for (int i = 0; i < 74; i++) xr[i] = xt[f][b + i];
  }

  // ---- wide: 64-tap ----
  float accw[8], acc_e0, acc_e1;
  #pragma unroll
  for (int k = 0; k < 8; k++) accw[k] = b64[k*3 + f];
  acc_e0 = accw[7]; acc_e1 = accw[0];
  {
    const float* kp = &k64s[f*512];
    #pragma unroll
    for (int t = 0; t < 64; t++){
      float4 wa = *(const float4*)(kp + t*8);
      float4 wb = *(const float4*)(kp + t*8 + 4);
      float xm = xr[8 + t];
      accw[0] = fmaf(xm, wa.x, accw[0]);
      accw[1] = fmaf(xm, wa.y, accw[1]);
      accw[2] = fmaf(xm, wa.z, accw[2]);
      accw[3] = fmaf(xm, wa.w, accw[3]);
      accw[4] = fmaf(xm, wb.x, accw[4]);
      accw[5] = fmaf(xm, wb.y, accw[5]);
      accw[6] = fmaf(xm, wb.z, accw[6]);
      accw[7] = fmaf(xm, wb.w, accw[7]);
      acc_e0 = fmaf(xr[6 + t],  wb.w, acc_e0);
      acc_e1 = fmaf(xr[10 + t], wa.x, acc_e1);
    }
  }
  float yw[10];
  yw[0] = (s > 0) ? 5.f*relu_(acc_e0) : 0.f;
  #pragma unroll
  for (int c = 1; c <= 8; c++) yw[c] = 5.f*relu_(accw[c-1]);
  yw[9] = (s < 1023) ? 5.f*relu_(acc_e1) : 0.f;

  // ---- mid: 16-tap ----
  float w16r[16];
  #pragma unroll
  for (int t = 0; t < 16; t++) w16r[t] = k16[f*16 + t];
  const float bb16 = b16[f];
  float ym[10];
  #pragma unroll
  for (int ci = 0; ci < 10; ci++){
    const int b = (ci == 0) ? 54 : ((ci == 9) ? 2 : 8*(ci-1));
    float a = bb16;
    #pragma unroll
    for (int t = 0; t < 16; t++) a = fmaf(xr[b + t], w16r[t], a);
    ym[ci] = relu_(a);
  }
  if (s == 0)    ym[0] = 0.f;
  if (s == 1023) ym[9] = 0.f;

  // ---- nar: 8-tap, max over 4 ----
  float w8r[8];
  #pragma unroll
  for (int t = 0; t < 8; t++) w8r[t] = k8[f*8 + t];
  const float bb8 = b8[f];
  float yn[10];
  #pragma unroll
  for (int ci = 0; ci < 10; ci++){
    float m = -3.0e38f;
    #pragma unroll
    for (int j2 = 0; j2 < 4; j2++){
      const int b = (ci == 0) ? (58 + 2*j2)
                  : ((ci == 9) ? (6 + 2*j2)
                               : (4 + 2*(4*(ci-1) + j2)));
      float a = bb8;
      #pragma unroll
      for (int t = 0; t < 8; t++) a = fmaf(xr[b + t], w8r[t], a);
      m = fmaxf(m, a);
    }
    yn[ci] = relu_(m);
  }
  if (s == 0)    yn[0] = 0.f;
  if (s == 1023) yn[9] = 0.f;

  // ---- conv3 + relu + pool2 -> flat ----
  {
    float c0 = kw3[f*3], c1 = kw3[f*3+1], c2 = kw3[f*3+2], bb = bw3[f];
    #pragma unroll
    for (int q = 0; q < 4; q++){
      float z0 = relu_(fmaf(c0, yw[2*q],   fmaf(c1, yw[2*q+1], fmaf(c2, yw[2*q+2], bb))));
      float z1 = relu_(fmaf(c0, yw[2*q+1], fmaf(c1, yw[2*q+2], fmaf(c2, yw[2*q+3], bb))));
      flat_s[lane][q*3 + f] = fmaxf(z0, z1);
    }
  }
  {
    float c0 = km3[f*3], c1 = km3[f*3+1], c2 = km3[f*3+2], bb = bm3[f];
    #pragma unroll
    for (int q = 0; q < 4; q++){
      float z0 = relu_(fmaf(c0, ym[2*q],   fmaf(c1, ym[2*q+1], fmaf(c2, ym[2*q+2], bb))));
      float z1 = relu_(fmaf(c0, ym[2*q+1], fmaf(c1, ym[2*q+2], fmaf(c2, ym[2*q+3], bb))));
      flat_s[lane][12 + q*3 + f] = fmaxf(z0, z1);
    }
  }
  {
    float c0 = kn3[f*3], c1 = kn3[f*3+1], c2 = kn3[f*3+2], bb = bn3[f];
    #pragma unroll
    for (int q = 0; q < 4; q++){
      float z0 = relu_(fmaf(c0, yn[2*q],   fmaf(c1, yn[2*q+1], fmaf(c2, yn[2*q+2], bb))));
      float z1 = relu_(fmaf(c0, yn[2*q+1], fmaf(c1, yn[2*q+2], fmaf(c2, yn[2*q+3], bb))));
      flat_s[lane][24 + q*3 + f] = fmaxf(z0, z1);
    }
  }
  __syncthreads();

  // ---- fc1 ----
  #pragma unroll
  for (int oi = 0; oi < 6; oi++){
    const int o = 6*f + oi;
    float acc = fc1b[o];
    const float4* wrow = (const float4*)(fc1w + o*36);
    const float4* frow = (const float4*)(&flat_s[lane][0]);
    #pragma unroll
    for (int i = 0; i < 9; i++){
      float4 wv = wrow[i], fv = frow[i];
      acc = fmaf(wv.x, fv.x, acc); acc = fmaf(wv.y, fv.y, acc);
      acc = fmaf(wv.z, fv.z, acc); acc = fmaf(wv.w, fv.w, acc);
    }
    h1_s[lane][o] = relu_(acc);
  }
  __syncthreads();

  // ---- fc2 ----
  #pragma unroll
  for (int ei = 0; ei < 2; ei++){
    const int e = 2*f + ei;
    float acc = fc2b[e];
    #pragma unroll
    for (int o = 0; o < 18; o++) acc = fmaf(h1_s[lane][o], fc2w[e*18 + o], acc);
    seq[(n*SL + s)*ED + e] = acc < 0.f ? 0.f : acc;
    seq6[lane][e] = acc < 0.f ? 0.f : acc;
  }
  __syncthreads();

  // ---- layer-0 qkv: thread = (head g = f, token = lane) ----
  {
    const int g = f;
    float sv[6];
    #pragma unroll
    for (int e = 0; e < 6; e++) sv[e] = seq6[lane][e];
    const float* W = inw;
    const float* B = inb;
    const int h2 = 2*g;
    float q0 = B[h2],   q1 = B[h2+1];
    float k0 = B[6+h2], k1 = B[7+h2];
    float v0 = B[12+h2], v1 = B[13+h2];
    #pragma unroll
    for (int e = 0; e < 6; e++){
      q0 = fmaf(sv[e], W[h2*6 + e],      q0);
      q1 = fmaf(sv[e], W[(h2+1)*6 + e],  q1);
      k0 = fmaf(sv[e], W[(6+h2)*6 + e],  k0);
      k1 = fmaf(sv[e], W[(7+h2)*6 + e],  k1);
      v0 = fmaf(sv[e], W[(12+h2)*6 + e], v0);
      v1 = fmaf(sv[e], W[(13+h2)*6 + e], v1);
    }
    const int nh = n*3 + g;
    kv4[nh*SL + s] = make_float4(k0*SCQK, k1*SCQK, v0, v1);
    qq [nh*SL + s] = make_float2(q0, q1);
  }
}

// ------------------------------ mega layer ----------------------------------
// grid 256 = (n 16) x (stile 16, 64 tokens); 512 threads = 8 waves.
// A: stage kv(3 heads, 48KB) -> attention (wave = 8 rows x 3 heads, lanes
//    span t; 4-step shfl + LDS group reduce)
// B: oproj + residual + LN1 -> sM
// C: FF, 2 passes of 1024 rows; weights staged chunk-major wcT[4][1024]
//    (16B/lane LDS pattern, no 64B-stride bank conflict); lane: 8 tok x rows
// D: FF 64-lane shfl reduce -> LN2 -> seq_out (+ next-layer qkv)
__global__ __launch_bounds__(512, 2) void layer_kernel(
  const float* __restrict__ seq_in, const float4* __restrict__ kv_in,
  const float2* __restrict__ q_in, const float* __restrict__ fccL,
  const float* __restrict__ owL, const float* __restrict__ obL,
  const float* __restrict__ l1wL, const float* __restrict__ l1bL,
  const float* __restrict__ f2bL, const float* __restrict__ l2wL,
  const float* __restrict__ l2bL,
  const float* __restrict__ WqN, const float* __restrict__ BqN,
  float* __restrict__ seq_out, float4* __restrict__ kv_out,
  float2* __restrict__ q_out, int has_next)
{
  __shared__ float4 uS[4096];     // 64KB: sKV[3][1024] + red | wcT[4][1024]
  __shared__ float attR[64][6];
  __shared__ float sM[64][6];
  __shared__ float fin[64][6];
  const int tid  = threadIdx.x;
  const int w    = tid >> 6;
  const int lane = tid & 63;
  const int n    = blockIdx.x >> 4;
  const int stile= blockIdx.x & 15;
  const int tok0 = stile << 6;
  float* redf = (float*)(uS + 3072);  // 2304 floats: [8w][3h][4g][8r? no: [..][8r][3v]] flattened

  // ---- A: stage kv for 3 heads ----
  for (int i = tid; i < 3072; i += 512){
    const int h = i >> 10, t = i & 1023;
    uS[i] = kv_in[(n*3 + h)*SL + t];
  }
  __syncthreads();

  // ---- A2: attention. wave w -> rows r0..r0+7, all 3 heads ----
  const int r0 = tok0 + w*8;
  #pragma unroll
  for (int h = 0; h < 3; h++){
    float q0[8], q1[8];
    {
      const float2* qp = q_in + (n*3 + h)*SL + r0;
      #pragma unroll
      for (int r = 0; r < 8; r++){ float2 qv = qp[r]; q0[r] = qv.x; q1[r] = qv.y; }
    }
    float l[8], o0[8], o1[8];
    #pragma unroll
    for (int r = 0; r < 8; r++){ l[r] = 0.f; o0[r] = 0.f; o1[r] = 0.f; }
    const float4* Kb = uS + h*1024;
    #pragma unroll 2
    for (int i = 0; i < 16; i++){
      float4 K = Kb[i*64 + lane];
      #pragma unroll
      for (int r = 0; r < 8; r++){
        float sc = fmaf(q0[r], K.x, q1[r]*K.y);
        float p  = fexp2_(sc);
        l[r] += p;
        o0[r] = fmaf(p, K.z, o0[r]);
        o1[r] = fmaf(p, K.w, o1[r]);
      }
    }
    // 4-step reduce -> 4 groups of 16 lanes
    #pragma unroll
    for (int r = 0; r < 8; r++){
      l[r]  += __shfl_xor(l[r], 1);  l[r]  += __shfl_xor(l[r], 2);
      l[r]  += __shfl_xor(l[r], 4);  l[r]  += __shfl_xor(l[r], 8);
      o0[r] += __shfl_xor(o0[r], 1); o0[r] += __shfl_xor(o0[r], 2);
      o0[r] += __shfl_xor(o0[r], 4); o0[r] += __shfl_xor(o0[r], 8);
      o1[r] += __shfl_xor(o1[r], 1); o1[r] += __shfl_xor(o1[r], 2);
      o1[r] += __shfl_xor(o1[r], 4); o1[r] += __shfl_xor(o1[r], 8);
    }
    {
      const int g = lane >> 4;
      const int base = ((w*3 + h)*4 + g)*24;
      #pragma unroll
      for (int r = 0; r < 8; r++){
        if ((lane & 15) == r){   // static reg index, predicated store
          redf[base + r*3 + 0] = l[r];
          redf[base + r*3 + 1] = o0[r];
          redf[base + r*3 + 2] = o1[r];
        }
      }
    }
  }
  __syncthreads();

  // ---- A3: finish reduce (8w x 3h x 8r = 192) ----
  if (tid < 192){
    const int w2 = tid / 24, rem = tid % 24, h2 = rem >> 3, r2 = rem & 7;
    const int base = ((w2*3 + h2)*4)*24 + r2*3;
    float L  = redf[base] + redf[base+24] + redf[base+48] + redf[base+72];
    float O0 = redf[base+1] + redf[base+25] + redf[base+49] + redf[base+73];
    float O1 = redf[base+2] + redf[base+26] + redf[base+50] + redf[base+74];
    const float inv = 1.0f / L;
    attR[w2*8 + r2][2*h2]   = O0*inv;
    attR[w2*8 + r2][2*h2+1] = O1*inv;
  }
  __syncthreads();

  // ---- B: oproj + residual + LN1 ----
  if (tid < 64){
    const int token = (n*SL + tok0 + tid);
    float av[6];
    #pragma unroll
    for (int e = 0; e < 6; e++) av[e] = attR[tid][e];
    float y[6]; float mu = 0.f;
    #pragma unroll
    for (int e = 0; e < 6; e++){
      float o = obL[e];
      #pragma unroll
      for (int e2 = 0; e2 < 6; e2++) o = fmaf(av[e2], owL[e*6 + e2], o);
      y[e] = seq_in[token*6 + e] + o;
      mu += y[e];
    }
    mu *= (1.f/6.f);
    float var = 0.f;
    #pragma unroll
    for (int e = 0; e < 6; e++){ float d = y[e] - mu; var = fmaf(d, d, var); }
    var *= (1.f/6.f);
    float rstd = rsqrtf(var + 1e-5f);
    #pragma unroll
    for (int e = 0; e < 6; e++)
      sM[tid][e] = (y[e] - mu)*rstd*l1wL[e] + l1bL[e];
  }

  // ---- C: FF, two passes of 1024 rows; acc persists ----
  float acc[8][6];
  #pragma unroll
  for (int t = 0; t < 8; t++)
    #pragma unroll
    for (int e = 0; e < 6; e++) acc[t][e] = 0.f;
  float sv[8][6];

  #pragma unroll
  for (int pass = 0; pass < 2; pass++){
    __syncthreads();  // prior users of uS done (attn data / pass-0 weights)
    {
      const float4* src = (const float4*)fccL + (size_t)pass*4096;
      for (int i = tid; i < 4096; i += 512){
        const int r = i >> 2, j = i & 3;
        uS[j*1024 + r] = src[i];   // chunk-major wcT[j][r]
      }
    }
    __syncthreads();
    // tokens w*8..w*8+7 (broadcast LDS reads)
    {
      const float* sp = &sM[w*8][0];
      #pragma unroll
      for (int t = 0; t < 8; t++)
        #pragma unroll
        for (int e = 0; e < 6; e++) sv[t][e] = sp[t*6 + e];
    }
    #pragma unroll 2
    for (int ii = 0; ii < 16; ii++){
      const int r = ii*64 + lane;
      float4 w0 = uS[r], w1 = uS[1024 + r], w2 = uS[2048 + r], w3 = uS[3072 + r];
      #pragma unroll
      for (int t = 0; t < 8; t++){
        float h = w1.z;
        h = fmaf(sv[t][0], w0.x, h); h = fmaf(sv[t][1], w0.y, h);
        h = fmaf(sv[t][2], w0.z, h); h = fmaf(sv[t][3], w0.w, h);
        h = fmaf(sv[t][4], w1.x, h); h = fmaf(sv[t][5], w1.y, h);
        h = relu_(h);
        acc[t][0] = fmaf(h, w2.x, acc[t][0]); acc[t][1] = fmaf(h, w2.y, acc[t][1]);
        acc[t][2] = fmaf(h, w2.z, acc[t][2]); acc[t][3] = fmaf(h, w2.w, acc[t][3]);
        acc[t][4] = fmaf(h, w3.x, acc[t][4]); acc[t][5] = fmaf(h, w3.y, acc[t][5]);
      }
    }
  }

  // ---- D: reduce across 64 lanes; lane 0 holds full sums for 8 tokens ----
  #pragma unroll
  for (int t = 0; t < 8; t++)
    #pragma unroll
    for (int e = 0; e < 6; e++){
      acc[t][e] += __shfl_xor(acc[t][e], 1);  acc[t][e] += __shfl_xor(acc[t][e], 2);
      acc[t][e] += __shfl_xor(acc[t][e], 4);  acc[t][e] += __shfl_xor(acc[t][e], 8);
      acc[t][e] += __shfl_xor(acc[t][e], 16); acc[t][e] += __shfl_xor(acc[t][e], 32);
    }
  if (lane == 0){
    #pragma unroll
    for (int t = 0; t < 8; t++)
      #pragma unroll
      for (int e = 0; e < 6; e++) fin[w*8 + t][e] = acc[t][e];
  }
  __syncthreads();

  // LN2 + seq_out (+ stash LN'd value in attR for qkv)
  if (tid < 64){
    float y[6]; float mu = 0.f;
    #pragma unroll
    for (int e = 0; e < 6; e++){
      y[e] = sM[tid][e] + fin[tid][e] + f2bL[e];
      mu += y[e];
    }
    mu *= (1.f/6.f);
    float var = 0.f;
    #pragma unroll
    for (int e = 0; e < 6; e++){ float d = y[e] - mu; var = fmaf(d, d, var); }
    var *= (1.f/6.f);
    float rstd = rsqrtf(var + 1e-5f);
    const int token = n*SL + tok0 + tid;
    #pragma unroll
    for (int e = 0; e < 6; e++){
      float v = (y[e] - mu)*rstd*l2wL[e] + l2bL[e];
      attR[tid][e] = v;
      seq_out[token*6 + e] = v;
    }
  }
  if (has_next){
    __syncthreads();
    if (tid < 192){
      const int g = tid >> 6, t = tid & 63;
      float sv2[6];
      #pragma unroll
      for (int e = 0; e < 6; e++) sv2[e] = attR[t][e];
      const int h2 = 2*g;
      float q0 = BqN[h2],   q1 = BqN[h2+1];
      float k0 = BqN[6+h2], k1 = BqN[7+h2];
      float v0 = BqN[12+h2], v1 = BqN[13+h2];
      #pragma unroll
      for (int e = 0; e < 6; e++){
        q0 = fmaf(sv2[e], WqN[h2*6 + e],      q0);
        q1 = fmaf(sv2[e], WqN[(h2+1)*6 + e],  q1);
        k0 = fmaf(sv2[e], WqN[(6+h2)*6 + e],  k0);
        k1 = fmaf(sv2[e], WqN[(7+h2)*6 + e],  k1);
        v0 = fmaf(sv2[e], WqN[(12+h2)*6 + e], v0);
        v1 = fmaf(sv2[e], WqN[(13+h2)*6 + e], v1);
      }
      const int nh = n*3 + g;
      kv_out[nh*SL + tok0 + t] = make_float4(k0*SCQK, k1*SCQK, v0, v1);
      q_out [nh*SL + tok0 + t] = make_float2(q0, q1);
    }
  }
}

// ------------------------------- head ----------------------------------------
__global__ __launch_bounds__(192) void final_kernel(
  const float* __restrict__ seq, const float* __restrict__ o1w,
  const float* __restrict__ o1b, const float* __restrict__ o2w,
  float* __restrict__ out)
{
  __shared__ float red[6][33];
  __shared__ float pooled[6];
  const int n = blockIdx.x, tid = threadIdx.x, e = tid >> 5, ch = tid & 31;
  float s = 0.f;
  for (int i = ch; i < 1024; i += 32) s += seq[(n*SL + i)*ED + e];
  red[e][ch] = s;
  __syncthreads();
  if (tid < 6){
    float t = 0.f;
    for (int i = 0; i < 32; i++) t += red[tid][i];
    pooled[tid] = fmaxf(t * (1.f/1024.f), 0.f);
  }
  __syncthreads();
  if (tid == 0){
    float o1[7];
    #pragma unroll
    for (int o = 0; o < 7; o++){
      float a = o1b[o];
      #pragma unroll
      for (int e2 = 0; e2 < 6; e2++) a = fmaf(pooled[e2], o1w[o*6 + e2], a);
      o1[o] = relu_(a);
    }
    float lg[4];
    #pragma unroll
    for (int c = 0; c < 4; c++){
      float a = 0.f;
      #pragma unroll
      for (int o = 0; o < 7; o++) a = fmaf(o1[o], o2w[c*7 + o], a);
      lg[c] = a;
    }
    float m = fmaxf(fmaxf(lg[0], lg[1]), fmaxf(lg[2], lg[3]));
    float sum = 0.f;
    #pragma unroll
    for (int c = 0; c < 4; c++) sum += expf(lg[c] - m);
    float lse = m + logf(sum);
    #pragma unroll
    for (int c = 0; c < 4; c++) out[n*4 + c] = lg[c] - lse;
  }
}

// ------------------------------- launch --------------------------------------
extern "C" void kernel_launch(void* const* d_in, const int* in_sizes, int n_in,
                              void* d_out, int out_size, void* d_ws, size_t ws_size,
                              hipStream_t stream)
{
  const float* x    = (const float*)d_in[0];
  const float* k64  = (const float*)d_in[1];
  const float* b64  = (const float*)d_in[2];
  const float* k16  = (const float*)d_in[3];
  const float* b16  = (const float*)d_in[4];
  const float* k8   = (const float*)d_in[5];
  const float* b8   = (const float*)d_in[6];
  const float* kw3  = (const float*)d_in[7];
  const float* bw3  = (const float*)d_in[8];
  const float* km3  = (const float*)d_in[9];
  const float* bm3  = (const float*)d_in[10];
  const float* kn3  = (const float*)d_in[11];
  const float* bn3  = (const float*)d_in[12];
  const float* fc1w = (const float*)d_in[13];
  const float* fc1b = (const float*)d_in[14];
  const float* fc2w = (const float*)d_in[15];
  const float* fc2b = (const float*)d_in[16];
  const float* inw  = (const float*)d_in[17];
  const float* inb  = (const float*)d_in[18];
  const float* ow   = (const float*)d_in[19];
  const float* ob   = (const float*)d_in[20];
  const float* l1w  = (const float*)d_in[21];
  const float* l1b  = (const float*)d_in[22];
  const float* l2w  = (const float*)d_in[23];
  const float* l2b  = (const float*)d_in[24];
  const float* f1w  = (const float*)d_in[25];
  const float* f1b  = (const float*)d_in[26];
  const float* f2w  = (const float*)d_in[27];
  const float* f2b  = (const float*)d_in[28];
  const float* o1w  = (const float*)d_in[29];
  const float* o1b  = (const float*)d_in[30];
  const float* o2w  = (const float*)d_in[31];
  float* out = (float*)d_out;

  float* w = (float*)d_ws;
  float*  seq_a = w;                        // 98304
  float*  seq_b = w + 98304;                // 98304
  float*  fcc   = w + 196608;               // 65536
  float4* kv4a  = (float4*)(w + 262144);    // 49152 f4 = 196608 fl
  float2* qqa   = (float2*)(w + 458752);    // 49152 f2 = 98304 fl
  float4* kv4b  = (float4*)(w + 557056);    // 196608 fl
  float2* qqb   = (float2*)(w + 753664);    // 98304 fl
  // total 851968 floats ~= 3.4 MB

  frontend_kernel<<<256, 192, 0, stream>>>(x, k64, b64, k16, b16, k8, b8,
      kw3, bw3, km3, bm3, kn3, bn3, fc1w, fc1b, fc2w, fc2b,
      f1w, f1b, f2w, inw, inb, fcc, seq_a, kv4a, qqa);

  layer_kernel<<<256, 512, 0, stream>>>(seq_a, kv4a, qqa, fcc,
      ow, ob, l1w, l1b, f2b, l2w, l2b,
      inw + 108, inb + 18, seq_b, kv4b, qqb, 1);

  layer_kernel<<<256, 512, 0, stream>>>(seq_b, kv4b, qqb, fcc + 32768,
      ow + 36, ob + 6, l1w + 6, l1b + 6, f2b + 6, l2w + 6, l2b + 6,
      (const float*)nullptr, (const float*)nullptr, seq_a,
      (float4*)nullptr, (float2*)nullptr, 0);

  final_kernel<<<16, 192, 0, stream>>>(seq_a, o1w, o1b, o2w, out);
}

// Round 6
// 86.185 us; speedup vs baseline: 1.1050x; 1.1050x over previous
//
#include <hip/hip_runtime.h>
#include <math.h>

// ---------------------------------------------------------------------------
// FluxAnomalyPredictionTF: F=3, E=6, H=3, d=2, FF=2048, N=16, T=2046, S=W=1024
// 7 dispatches: frontend(+fcc+qkv0) -> attn0 -> ff0 -> ffln0(+qkv1) ->
//               attn1 -> ff1 -> final(+ffln1)
// R6: ff split 8 slices (grid 1024, 4 blocks/CU) for occupancy; R4 structure.
// ---------------------------------------------------------------------------

#define NB 16
#define TL 2046
#define SL 1024
#define ED 6

__device__ __forceinline__ float relu_(float a){ return fmaxf(a, 0.f); }
__device__ __forceinline__ float fexp2_(float x){ return __builtin_amdgcn_exp2f(x); }

#define SCQK 1.0201265650432017f  // (1/sqrt(2)) * log2(e)

// ------------------------------ frontend -----------------------------------
__global__ __launch_bounds__(192) void frontend_kernel(
  const float* __restrict__ x, const float* __restrict__ k64,
  const float* __restrict__ b64, const float* __restrict__ k16, const float* __restrict__ b16,
  const float* __restrict__ k8,  const float* __restrict__ b8,
  const float* __restrict__ kw3, const float* __restrict__ bw3,
  const float* __restrict__ km3, const float* __restrict__ bm3,
  const float* __restrict__ kn3, const float* __restrict__ bn3,
  const float* __restrict__ fc1w, const float* __restrict__ fc1b,
  const float* __restrict__ fc2w, const float* __restrict__ fc2b,
  const float* __restrict__ f1w, const float* __restrict__ f1b,
  const float* __restrict__ f2w,
  const float* __restrict__ inw, const float* __restrict__ inb,
  float* __restrict__ fcc, float* __restrict__ seq,
  float4* __restrict__ kv4, float2* __restrict__ qq)
{
  __shared__ float xt[3][200];
  __shared__ float k64s[3*64*8];
  __shared__ float flat_s[64][44];
  __shared__ float h1_s[64][20];
  __shared__ float seq6[64][6];
  const int tid  = threadIdx.x;
  const int f    = tid >> 6;
  const int lane = tid & 63;
  const int n    = blockIdx.x >> 4;
  const int s0   = (blockIdx.x & 15) << 6;
  const int s    = s0 + lane;

  // fcc[l][j][16]: [0..5]=f1w row j, [6]=f1b[j], [8..13]=f2w[:,j]
  for (int i = blockIdx.x*192 + tid; i < 2*2048*16; i += 256*192){
    int l = i >> 15, r = i & 32767, j = r >> 4, c = r & 15;
    float v = 0.f;
    if (c < 6)       v = f1w[(l*2048 + j)*6 + c];
    else if (c == 6) v = f1b[l*2048 + j];
    else if (c >= 8 && c < 14) v = f2w[(l*6 + (c-8))*2048 + j];
    fcc[i] = v;
  }

  for (int i = tid; i < 600; i += 192){
    int ff = i / 200, pos = i - ff*200;
    int xp = 2*s0 - 39 + pos;
    xt[ff][pos] = (xp >= 0 && xp < TL) ? x[(n*TL + xp)*3 + ff] : 0.f;
  }
  for (int i = tid; i < 1536; i += 192){
    int ff = i >> 9, r = i & 511, t = r >> 3, k = r & 7;
    k64s[i] = k64[k*192 + ff*64 + t];
  }
  __syncthreads();

  float xr[74];
  {
    const int b = 2*lane;
    #pragma unroll
    for (int i = 0; i < 74; i++) xr[i] = xt[f][b + i];
  }

  // ---- wide: 64-tap ----
  float accw[8], acc_e0, acc_e1;
  #pragma unroll
  for (int k = 0; k < 8; k++) accw[k] = b64[k*3 + f];
  acc_e0 = accw[7]; acc_e1 = accw[0];
  {
    const float* kp = &k64s[f*512];
    #pragma unroll
    for (int t = 0; t < 64; t++){
      float4 wa = *(const float4*)(kp + t*8);
      float4 wb = *(const float4*)(kp + t*8 + 4);
      float xm = xr[8 + t];
      accw[0] = fmaf(xm, wa.x, accw[0]);
      accw[1] = fmaf(xm, wa.y, accw[1]);
      accw[2] = fmaf(xm, wa.z, accw[2]);
      accw[3] = fmaf(xm, wa.w, accw[3]);
      accw[4] = fmaf(xm, wb.x, accw[4]);
      accw[5] = fmaf(xm, wb.y, accw[5]);
      accw[6] = fmaf(xm, wb.z, accw[6]);
      accw[7] = fmaf(xm, wb.w, accw[7]);
      acc_e0 = fmaf(xr[6 + t],  wb.w, acc_e0);
      acc_e1 = fmaf(xr[10 + t], wa.x, acc_e1);
    }
  }
  float yw[10];
  yw[0] = (s > 0) ? 5.f*relu_(acc_e0) : 0.f;
  #pragma unroll
  for (int c = 1; c <= 8; c++) yw[c] = 5.f*relu_(accw[c-1]);
  yw[9] = (s < 1023) ? 5.f*relu_(acc_e1) : 0.f;

  // ---- mid: 16-tap ----
  float w16r[16];
  #pragma unroll
  for (int t = 0; t < 16; t++) w16r[t] = k16[f*16 + t];
  const float bb16 = b16[f];
  float ym[10];
  #pragma unroll
  for (int ci = 0; ci < 10; ci++){
    const int b = (ci == 0) ? 54 : ((ci == 9) ? 2 : 8*(ci-1));
    float a = bb16;
    #pragma unroll
    for (int t = 0; t < 16; t++) a = fmaf(xr[b + t], w16r[t], a);
    ym[ci] = relu_(a);
  }
  if (s == 0)    ym[0] = 0.f;
  if (s == 1023) ym[9] = 0.f;

  // ---- nar: 8-tap, max over 4 ----
  float w8r[8];
  #pragma unroll
  for (int t = 0; t < 8; t++) w8r[t] = k8[f*8 + t];
  const float bb8 = b8[f];
  float yn[10];
  #pragma unroll
  for (int ci = 0; ci < 10; ci++){
    float m = -3.0e38f;
    #pragma unroll
    for (int j2 = 0; j2 < 4; j2++){
      const int b = (ci == 0) ? (58 + 2*j2)
                  : ((ci == 9) ? (6 + 2*j2)
                               : (4 + 2*(4*(ci-1) + j2)));
      float a = bb8;
      #pragma unroll
      for (int t = 0; t < 8; t++) a = fmaf(xr[b + t], w8r[t], a);
      m = fmaxf(m, a);
    }
    yn[ci] = relu_(m);
  }
  if (s == 0)    yn[0] = 0.f;
  if (s == 1023) yn[9] = 0.f;

  // ---- conv3 + relu + pool2 -> flat ----
  {
    float c0 = kw3[f*3], c1 = kw3[f*3+1], c2 = kw3[f*3+2], bb = bw3[f];
    #pragma unroll
    for (int q = 0; q < 4; q++){
      float z0 = relu_(fmaf(c0, yw[2*q],   fmaf(c1, yw[2*q+1], fmaf(c2, yw[2*q+2], bb))));
      float z1 = relu_(fmaf(c0, yw[2*q+1], fmaf(c1, yw[2*q+2], fmaf(c2, yw[2*q+3], bb))));
      flat_s[lane][q*3 + f] = fmaxf(z0, z1);
    }
  }
  {
    float c0 = km3[f*3], c1 = km3[f*3+1], c2 = km3[f*3+2], bb = bm3[f];
    #pragma unroll
    for (int q = 0; q < 4; q++){
      float z0 = relu_(fmaf(c0, ym[2*q],   fmaf(c1, ym[2*q+1], fmaf(c2, ym[2*q+2], bb))));
      float z1 = relu_(fmaf(c0, ym[2*q+1], fmaf(c1, ym[2*q+2], fmaf(c2, ym[2*q+3], bb))));
      flat_s[lane][12 + q*3 + f] = fmaxf(z0, z1);
    }
  }
  {
    float c0 = kn3[f*3], c1 = kn3[f*3+1], c2 = kn3[f*3+2], bb = bn3[f];
    #pragma unroll
    for (int q = 0; q < 4; q++){
      float z0 = relu_(fmaf(c0, yn[2*q],   fmaf(c1, yn[2*q+1], fmaf(c2, yn[2*q+2], bb))));
      float z1 = relu_(fmaf(c0, yn[2*q+1], fmaf(c1, yn[2*q+2], fmaf(c2, yn[2*q+3], bb))));
      flat_s[lane][24 + q*3 + f] = fmaxf(z0, z1);
    }
  }
  __syncthreads();

  // ---- fc1 ----
  #pragma unroll
  for (int oi = 0; oi < 6; oi++){
    const int o = 6*f + oi;
    float acc = fc1b[o];
    const float4* wrow = (const float4*)(fc1w + o*36);
    const float4* frow = (const float4*)(&flat_s[lane][0]);
    #pragma unroll
    for (int i = 0; i < 9; i++){
      float4 wv = wrow[i], fv = frow[i];
      acc = fmaf(wv.x, fv.x, acc); acc = fmaf(wv.y, fv.y, acc);
      acc = fmaf(wv.z, fv.z, acc); acc = fmaf(wv.w, fv.w, acc);
    }
    h1_s[lane][o] = relu_(acc);
  }
  __syncthreads();

  // ---- fc2 ----
  #pragma unroll
  for (int ei = 0; ei < 2; ei++){
    const int e = 2*f + ei;
    float acc = fc2b[e];
    #pragma unroll
    for (int o = 0; o < 18; o++) acc = fmaf(h1_s[lane][o], fc2w[e*18 + o], acc);
    seq[(n*SL + s)*ED + e] = acc < 0.f ? 0.f : acc;
    seq6[lane][e] = acc < 0.f ? 0.f : acc;
  }
  __syncthreads();

  // ---- layer-0 qkv: thread = (head g = f, token = lane) ----
  {
    const int g = f;
    float sv[6];
    #pragma unroll
    for (int e = 0; e < 6; e++) sv[e] = seq6[lane][e];
    const float* W = inw;
    const float* B = inb;
    const int h2 = 2*g;
    float q0 = B[h2],   q1 = B[h2+1];
    float k0 = B[6+h2], k1 = B[7+h2];
    float v0 = B[12+h2], v1 = B[13+h2];
    #pragma unroll
    for (int e = 0; e < 6; e++){
      q0 = fmaf(sv[e], W[h2*6 + e],      q0);
      q1 = fmaf(sv[e], W[(h2+1)*6 + e],  q1);
      k0 = fmaf(sv[e], W[(6+h2)*6 + e],  k0);
      k1 = fmaf(sv[e], W[(7+h2)*6 + e],  k1);
      v0 = fmaf(sv[e], W[(12+h2)*6 + e], v0);
      v1 = fmaf(sv[e], W[(13+h2)*6 + e], v1);
    }
    const int nh = n*3 + g;
    kv4[nh*SL + s] = make_float4(k0*SCQK, k1*SCQK, v0, v1);
    qq [nh*SL + s] = make_float2(q0, q1);
  }
}

// ------------------------------ attention ----------------------------------
// grid (16 rb, 3 h, 16 n); 256 thr = 4 waves. Wave owns 16 q-rows; lanes span
// t. q0/q1 wave-uniform. 3-level shfl reduce + LDS phase2.
__global__ __launch_bounds__(256) void attn_kernel(
  const float4* __restrict__ kv4, const float2* __restrict__ qq,
  float* __restrict__ att_out)
{
  __shared__ float4 sKV[1024];
  __shared__ float red[4][8][16][3];
  const int tid  = threadIdx.x;
  const int w    = tid >> 6;
  const int lane = tid & 63;
  const int rb   = blockIdx.x << 6;
  const int h    = blockIdx.y;
  const int n    = blockIdx.z;
  const int nh   = n*3 + h;

  const float4* kvp = kv4 + nh*SL;
  #pragma unroll
  for (int i = 0; i < 4; i++) sKV[tid + i*256] = kvp[tid + i*256];

  const int r0 = rb + w*16;
  float q0[16], q1[16];
  {
    const float2* qp = qq + nh*SL + r0;
    #pragma unroll
    for (int r = 0; r < 16; r++){ float2 qv = qp[r]; q0[r] = qv.x; q1[r] = qv.y; }
  }
  __syncthreads();

  float l[16], o0[16], o1[16];
  #pragma unroll
  for (int r = 0; r < 16; r++){ l[r] = 0.f; o0[r] = 0.f; o1[r] = 0.f; }

  #pragma unroll 2
  for (int i = 0; i < 16; i++){
    float4 K = sKV[i*64 + lane];
    #pragma unroll
    for (int r = 0; r < 16; r++){
      float sc = fmaf(q0[r], K.x, q1[r]*K.y);
      float p  = fexp2_(sc);
      l[r] += p;
      o0[r] = fmaf(p, K.z, o0[r]);
      o1[r] = fmaf(p, K.w, o1[r]);
    }
  }

  #pragma unroll
  for (int r = 0; r < 16; r++){
    l[r]  += __shfl_xor(l[r], 1);  l[r]  += __shfl_xor(l[r], 2);  l[r]  += __shfl_xor(l[r], 4);
    o0[r] += __shfl_xor(o0[r], 1); o0[r] += __shfl_xor(o0[r], 2); o0[r] += __shfl_xor(o0[r], 4);
    o1[r] += __shfl_xor(o1[r], 1); o1[r] += __shfl_xor(o1[r], 2); o1[r] += __shfl_xor(o1[r], 4);
  }
  {
    const int g = lane >> 3;
    #pragma unroll
    for (int r = 0; r < 16; r++){
      if ((lane & 7) == (r & 7)){
        red[w][g][r][0] = l[r];
        red[w][g][r][1] = o0[r];
        red[w][g][r][2] = o1[r];
      }
    }
  }
  __syncthreads();

  if (tid < 64){
    const int ww = tid >> 4, r = tid & 15;
    float L = 0.f, O0 = 0.f, O1 = 0.f;
    #pragma unroll
    for (int g = 0; g < 8; g++){
      L  += red[ww][g][r][0];
      O0 += red[ww][g][r][1];
      O1 += red[ww][g][r][2];
    }
    const int row = rb + ww*16 + r;
    const float inv = 1.0f / L;
    float* orow = att_out + (n*SL + row)*ED + 2*h;
    orow[0] = O0*inv; orow[1] = O1*inv;
  }
}

// ------------------- fused oproj+LN1 + FF partial ---------------------------
// grid 1024 = 128 token-tiles(128 tok) * 8 j-slices(256 rows); 256 threads.
// 16 KB weight stage -> 4 blocks/CU (16 waves/CU) for latency hiding.
__global__ __launch_bounds__(256) void ff_kernel(
  const float* __restrict__ seq_in, const float* __restrict__ att,
  const float* __restrict__ fcc,
  const float* __restrict__ ow, const float* __restrict__ ob,
  const float* __restrict__ l1w, const float* __restrict__ l1b,
  float* __restrict__ seq_mid, float* __restrict__ ffp, int layer)
{
  __shared__ float wc[256][16];  // 16 KB
  __shared__ float sM[128][6];
  const int tid   = threadIdx.x;
  const int tile  = blockIdx.x >> 3;
  const int slice = blockIdx.x & 7;
  const int tok0  = tile * 128;

  const float4* FC = (const float4*)(fcc + (size_t)(layer*2048 + slice*256)*16);
  for (int i = tid; i < 1024; i += 256)
    ((float4*)wc)[i] = FC[i];

  if (tid < 128){
    const int token = tok0 + tid;
    const float* a  = att + token*6;
    const float* W  = ow + layer*36;
    float av[6];
    #pragma unroll
    for (int e = 0; e < 6; e++) av[e] = a[e];
    float y[6]; float mu = 0.f;
    #pragma unroll
    for (int e = 0; e < 6; e++){
      float o = ob[layer*6 + e];
      #pragma unroll
      for (int e2 = 0; e2 < 6; e2++) o = fmaf(av[e2], W[e*6 + e2], o);
      y[e] = seq_in[token*6 + e] + o;
      mu += y[e];
    }
    mu *= (1.f/6.f);
    float var = 0.f;
    #pragma unroll
    for (int e = 0; e < 6; e++){ float d = y[e] - mu; var = fmaf(d, d, var); }
    var *= (1.f/6.f);
    float rstd = rsqrtf(var + 1e-5f);
    #pragma unroll
    for (int e = 0; e < 6; e++)
      sM[tid][e] = (y[e] - mu)*rstd*l1w[layer*6 + e] + l1b[layer*6 + e];
  }
  __syncthreads();

  const int w = tid >> 6, lane = tid & 63, tp = lane >> 2, ss = lane & 3;

  float sv[8][6];
  {
    const float* sp = &sM[tp*8][0];
    #pragma unroll
    for (int t = 0; t < 8; t++)
      #pragma unroll
      for (int e = 0; e < 6; e++) sv[t][e] = sp[t*6 + e];
  }
  float acc[8][6];
  #pragma unroll
  for (int t = 0; t < 8; t++)
    #pragma unroll
    for (int e = 0; e < 6; e++) acc[t][e] = 0.f;

  // wave w -> rows [w*64, w*64+64), lane-group ss interleaved by 4
  const int rb = w*64 + ss;
  #pragma unroll 2
  for (int i = 0; i < 16; i++){
    const float4* wr = (const float4*)&wc[rb + i*4][0];
    float4 w0 = wr[0], w1 = wr[1], w2 = wr[2], w3 = wr[3];
    #pragma unroll
    for (int t = 0; t < 8; t++){
      float h = w1.z;
      h = fmaf(sv[t][0], w0.x, h); h = fmaf(sv[t][1], w0.y, h);
      h = fmaf(sv[t][2], w0.z, h); h = fmaf(sv[t][3], w0.w, h);
      h = fmaf(sv[t][4], w1.x, h); h = fmaf(sv[t][5], w1.y, h);
      h = relu_(h);
      acc[t][0] = fmaf(h, w2.x, acc[t][0]); acc[t][1] = fmaf(h, w2.y, acc[t][1]);
      acc[t][2] = fmaf(h, w2.z, acc[t][2]); acc[t][3] = fmaf(h, w2.w, acc[t][3]);
      acc[t][4] = fmaf(h, w3.x, acc[t][4]); acc[t][5] = fmaf(h, w3.y, acc[t][5]);
    }
  }

  #pragma unroll
  for (int t = 0; t < 8; t++)
    #pragma unroll
    for (int e = 0; e < 6; e++){
      acc[t][e] += __shfl_xor(acc[t][e], 1);
      acc[t][e] += __shfl_xor(acc[t][e], 2);
    }
  __syncthreads();   // reuse wc as reduction scratch
  float* red = (float*)wc; // [4 waves][16 tp][48] = 3072 floats <= 4096
  if (ss == 0){
    #pragma unroll
    for (int t = 0; t < 8; t++)
      #pragma unroll
      for (int e = 0; e < 6; e++) red[(w*16 + tp)*48 + t*6 + e] = acc[t][e];
  }
  __syncthreads();
  for (int i = tid; i < 768; i += 256){
    const int tl = i / 6, e = i - tl*6;
    const int rtp = tl >> 3, rt = tl & 7;
    float sum = red[(0*16 + rtp)*48 + rt*6 + e]
              + red[(1*16 + rtp)*48 + rt*6 + e]
              + red[(2*16 + rtp)*48 + rt*6 + e]
              + red[(3*16 + rtp)*48 + rt*6 + e];
    ffp[(size_t)(slice*16384 + tok0 + tl)*6 + e] = sum;
  }
  if (slice == 0 && tid < 128){
    #pragma unroll
    for (int e = 0; e < 6; e++) seq_mid[(tok0 + tid)*6 + e] = sM[tid][e];
  }
}

// ------------------- FF-sum + LN2 + next-layer qkv --------------------------
__global__ __launch_bounds__(64) void ffln_kernel(
  const float* __restrict__ seq_mid, const float* __restrict__ ffp,
  const float* __restrict__ f2b, const float* __restrict__ lw,
  const float* __restrict__ lb,
  const float* __restrict__ Wq, const float* __restrict__ Bq,
  float* __restrict__ seq_out, float4* __restrict__ kv4, float2* __restrict__ qq)
{
  const int tok = blockIdx.x*64 + threadIdx.x;
  float y[6]; float mu = 0.f;
  #pragma unroll
  for (int e = 0; e < 6; e++){
    float v = seq_mid[tok*6 + e] + f2b[e];
    #pragma unroll
    for (int s2 = 0; s2 < 8; s2++)
      v += ffp[(size_t)(s2*16384 + tok)*6 + e];
    y[e] = v; mu += v;
  }
  mu *= (1.f/6.f);
  float var = 0.f;
  #pragma unroll
  for (int e = 0; e < 6; e++){ float d = y[e] - mu; var = fmaf(d, d, var); }
  var *= (1.f/6.f);
  float rstd = rsqrtf(var + 1e-5f);
  float sv[6];
  #pragma unroll
  for (int e = 0; e < 6; e++){
    sv[e] = (y[e] - mu)*rstd*lw[e] + lb[e];
    seq_out[tok*6 + e] = sv[e];
  }

  const int n = tok >> 10, t = tok & 1023;
  #pragma unroll
  for (int g = 0; g < 3; g++){
    const int h2 = 2*g;
    float q0 = Bq[h2],   q1 = Bq[h2+1];
    float k0 = Bq[6+h2], k1 = Bq[7+h2];
    float v0 = Bq[12+h2], v1 = Bq[13+h2];
    #pragma unroll
    for (int e = 0; e < 6; e++){
      q0 = fmaf(sv[e], Wq[h2*6 + e],      q0);
      q1 = fmaf(sv[e], Wq[(h2+1)*6 + e],  q1);
      k0 = fmaf(sv[e], Wq[(6+h2)*6 + e],  k0);
      k1 = fmaf(sv[e], Wq[(7+h2)*6 + e],  k1);
      v0 = fmaf(sv[e], Wq[(12+h2)*6 + e], v0);
      v1 = fmaf(sv[e], Wq[(13+h2)*6 + e], v1);
    }
    const int nh = n*3 + g;
    kv4[nh*SL + t] = make_float4(k0*SCQK, k1*SCQK, v0, v1);
    qq [nh*SL + t] = make_float2(q0, q1);
  }
}

// --------------------- head (+ layer-1 FF-sum + LN2) -------------------------
// 16 blocks x 1024 thr; thread = one token's LN2; wave+block reduce -> head.
__global__ __launch_bounds__(1024) void final_kernel(
  const float* __restrict__ seq_mid, const float* __restrict__ ffp,
  const float* __restrict__ f2b, const float* __restrict__ lw,
  const float* __restrict__ lb,
  const float* __restrict__ o1w, const float* __restrict__ o1b,
  const float* __restrict__ o2w, float* __restrict__ out)
{
  __shared__ float fred[16][6];
  __shared__ float pooled[6];
  const int n = blockIdx.x, tid = threadIdx.x;
  const int tok = n*SL + tid;

  float y[6]; float mu = 0.f;
  #pragma unroll
  for (int e = 0; e < 6; e++){
    float v = seq_mid[tok*6 + e] + f2b[e];
    #pragma unroll
    for (int s2 = 0; s2 < 8; s2++)
      v += ffp[(size_t)(s2*16384 + tok)*6 + e];
    y[e] = v; mu += v;
  }
  mu *= (1.f/6.f);
  float var = 0.f;
  #pragma unroll
  for (int e = 0; e < 6; e++){ float d = y[e] - mu; var = fmaf(d, d, var); }
  var *= (1.f/6.f);
  float rstd = rsqrtf(var + 1e-5f);
  float psum[6];
  #pragma unroll
  for (int e = 0; e < 6; e++) psum[e] = (y[e] - mu)*rstd*lw[e] + lb[e];

  #pragma unroll
  for (int e = 0; e < 6; e++){
    psum[e] += __shfl_xor(psum[e], 1);  psum[e] += __shfl_xor(psum[e], 2);
    psum[e] += __shfl_xor(psum[e], 4);  psum[e] += __shfl_xor(psum[e], 8);
    psum[e] += __shfl_xor(psum[e], 16); psum[e] += __shfl_xor(psum[e], 32);
  }
  if ((tid & 63) == 0){
    #pragma unroll
    for (int e = 0; e < 6; e++) fred[tid >> 6][e] = psum[e];
  }
  __syncthreads();
  if (tid < 6){
    float t = 0.f;
    #pragma unroll
    for (int wv = 0; wv < 16; wv++) t += fred[wv][tid];
    pooled[tid] = fmaxf(t * (1.f/1024.f), 0.f);
  }
  __syncthreads();
  if (tid == 0){
    float o1[7];
    #pragma unroll
    for (int o = 0; o < 7; o++){
      float a = o1b[o];
      #pragma unroll
      for (int e2 = 0; e2 < 6; e2++) a = fmaf(pooled[e2], o1w[o*6 + e2], a);
      o1[o] = relu_(a);
    }
    float lg[4];
    #pragma unroll
    for (int c = 0; c < 4; c++){
      float a = 0.f;
      #pragma unroll
      for (int o = 0; o < 7; o++) a = fmaf(o1[o], o2w[c*7 + o], a);
      lg[c] = a;
    }
    float m = fmaxf(fmaxf(lg[0], lg[1]), fmaxf(lg[2], lg[3]));
    float sum = 0.f;
    #pragma unroll
    for (int c = 0; c < 4; c++) sum += expf(lg[c] - m);
    float lse = m + logf(sum);
    #pragma unroll
    for (int c = 0; c < 4; c++) out[n*4 + c] = lg[c] - lse;
  }
}

// ------------------------------- launch --------------------------------------
extern "C" void kernel_launch(void* const* d_in, const int* in_sizes, int n_in,
                              void* d_out, int out_size, void* d_ws, size_t ws_size,
                              hipStream_t stream)
{
  const float* x    = (const float*)d_in[0];
  const float* k64  = (const float*)d_in[1];
  const float* b64  = (const float*)d_in[2];
  const float* k16  = (const float*)d_in[3];
  const float* b16  = (const float*)d_in[4];
  const float* k8   = (const float*)d_in[5];
  const float* b8   = (const float*)d_in[6];
  const float* kw3  = (const float*)d_in[7];
  const float* bw3  = (const float*)d_in[8];
  const float* km3  = (const float*)d_in[9];
  const float* bm3  = (const float*)d_in[10];
  const float* kn3  = (const float*)d_in[11];
  const float* bn3  = (const float*)d_in[12];
  const float* fc1w = (const float*)d_in[13];
  const float* fc1b = (const float*)d_in[14];
  const float* fc2w = (const float*)d_in[15];
  const float* fc2b = (const float*)d_in[16];
  const float* inw  = (const float*)d_in[17];
  const float* inb  = (const float*)d_in[18];
  const float* ow   = (const float*)d_in[19];
  const float* ob   = (const float*)d_in[20];
  const float* l1w  = (const float*)d_in[21];
  const float* l1b  = (const float*)d_in[22];
  const float* l2w  = (const float*)d_in[23];
  const float* l2b  = (const float*)d_in[24];
  const float* f1w  = (const float*)d_in[25];
  const float* f1b  = (const float*)d_in[26];
  const float* f2w  = (const float*)d_in[27];
  const float* f2b  = (const float*)d_in[28];
  const float* o1w  = (const float*)d_in[29];
  const float* o1b  = (const float*)d_in[30];
  const float* o2w  = (const float*)d_in[31];
  float* out = (float*)d_out;

  float* w = (float*)d_ws;
  float*  seq_a   = w;                        // 98304
  float*  seq_b   = w + 98304;                // 98304
  float*  att     = w + 196608;               // 98304
  float*  seq_mid = w + 294912;               // 98304
  float*  ffp     = w + 393216;               // 786432 (8 slices)
  float*  fcc     = w + 1179648;              // 65536
  float4* kv4     = (float4*)(w + 1245184);   // 196608 floats
  float2* qq      = (float2*)(w + 1441792);   // 98304 floats
  // total 1540096 floats ~= 6.2 MB

  frontend_kernel<<<256, 192, 0, stream>>>(x, k64, b64, k16, b16, k8, b8,
      kw3, bw3, km3, bm3, kn3, bn3, fc1w, fc1b, fc2w, fc2b,
      f1w, f1b, f2w, inw, inb, fcc, seq_a, kv4, qq);

  dim3 agrid(16, 3, 16);
  attn_kernel<<<agrid, 256, 0, stream>>>(kv4, qq, att);
  ff_kernel<<<1024, 256, 0, stream>>>(seq_a, att, fcc, ow, ob, l1w, l1b,
      seq_mid, ffp, 0);
  ffln_kernel<<<256, 64, 0, stream>>>(seq_mid, ffp, f2b, l2w, l2b,
      inw + 108, inb + 18, seq_b, kv4, qq);

  attn_kernel<<<agrid, 256, 0, stream>>>(kv4, qq, att);
  ff_kernel<<<1024, 256, 0, stream>>>(seq_b, att, fcc, ow, ob, l1w, l1b,
      seq_mid, ffp, 1);
  final_kernel<<<16, 1024, 0, stream>>>(seq_mid, ffp, f2b + 6, l2w + 6, l2b + 6,
      o1w, o1b, o2w, out);
}